// Round 2
// baseline (880.002 us; speedup 1.0000x reference)
//
#include <hip/hip_runtime.h>
#include <math.h>

// ArcFace loss, N=2048 rows, C=85742 cols, fp32 in, scalar fp32 out.
//
// loss_i = logsumexp_j(logits) - logits[target], logits = 32*cos except the
// target column which gets 32*phi.  Only ONE column differs, so stream the
// plain 32*cos logsumexp and patch the target column afterwards:
//   s     = sum_j 2^(K*(c_j - 1))          (K = 32*log2(e); 2^K factored out)
//   s_mod = s - 2^(K*(c_t-1)) + 2^(K*(phi_t-1))
//   loss  = ln2*log2(s_mod) + 32 - 32*phi_t
// Exponents in [-92.3, 0]: no overflow; row max ~= 1 so s >= ~1 (no
// destructive underflow).  Branchless hot loop, no online max.
//
// Vectorization: row pitch = 342968 B = 8 mod 16, so odd rows are 8- but not
// 16-byte aligned.  Shift the float4 body by 2 elements on odd rows
// (85740 = 4*21435 exactly); thread 0 mops up the 2 leftover elements.

#define NROWS 2048
#define NCOLS 85742
#define C4    21435                   // float4 body count (85740/4)

#define COS_M 0.8775825618903728f
#define SIN_M 0.479425538604203f
#define TH   (-0.8775825618903728f)   // cos(pi - 0.5)
#define MM    0.2397127693021015f     // sin(pi - 0.5) * 0.5
#define KLOG2 46.16624130844683f      // 32 * log2(e)
#define LN2   0.6931471805599453f

__device__ __forceinline__ float exp2_fast(float x) {
#if __has_builtin(__builtin_amdgcn_exp2f)
    return __builtin_amdgcn_exp2f(x);   // single v_exp_f32
#else
    return exp2f(x);
#endif
}

__device__ __forceinline__ float clamp1(float x) {
    return fminf(1.0f, fmaxf(-1.0f, x));        // -> v_med3_f32
}

__device__ __forceinline__ float term(float c) {
    return exp2_fast(fmaf(KLOG2, clamp1(c), -KLOG2));
}

__global__ __launch_bounds__(256) void arcface_loss_kernel(
    const float* __restrict__ cosine,
    const int*   __restrict__ targets,
    float*       __restrict__ out)
{
    const int row = blockIdx.x;
    const int tid = threadIdx.x;
    const size_t base = (size_t)row * NCOLS;
    const float* __restrict__ rowp = cosine + base;

    // Odd rows: start is 8-aligned only; shift body by 2 elems to 16B-align.
    const int shift = (row & 1) ? 2 : 0;
    const float4* __restrict__ p4 = (const float4*)(rowp + shift);

    // 4 independent accumulators break the serial v_add_f32 chain.
    float s0 = 0.0f, s1 = 0.0f, s2 = 0.0f, s3 = 0.0f;
#pragma unroll 4
    for (int j = tid; j < C4; j += 256) {
        float4 v = p4[j];
        s0 += term(v.x);
        s1 += term(v.y);
        s2 += term(v.z);
        s3 += term(v.w);
    }
    float s = (s0 + s1) + (s2 + s3);

    // 2 leftover elements: head (odd rows) or tail (even rows), 8B aligned.
    if (tid == 0) {
        const float2 v = *(const float2*)(rowp + (shift ? 0 : 4 * C4));
        s += term(v.x) + term(v.y);
    }

    // Wave-64 shuffle reduction.
#pragma unroll
    for (int off = 32; off > 0; off >>= 1)
        s += __shfl_down(s, off, 64);

    __shared__ float ws[4];
    const int wave = tid >> 6;
    const int lane = tid & 63;
    if (lane == 0) ws[wave] = s;
    __syncthreads();

    if (tid == 0) {
        float st = ws[0] + ws[1] + ws[2] + ws[3];

        const int t = targets[row];
        float ct = clamp1(cosine[base + (size_t)t]);
        float sn = sqrtf(fminf(1.0f, fmaxf(0.0f, 1.0f - ct * ct)));
        float phi = ct * COS_M - sn * SIN_M;          // cos(theta + m)
        phi = (ct > TH) ? phi : (ct - MM);            // fallback branch

        // Patch the target column (same exp2(fma) form as the hot loop).
        float smod = st - exp2_fast(fmaf(KLOG2, ct,  -KLOG2))
                        + exp2_fast(fmaf(KLOG2, phi, -KLOG2));

        float loss = LN2 * log2f(smod) + 32.0f - 32.0f * phi;
        atomicAdd(out, loss * (1.0f / (float)NROWS));
    }
}

extern "C" void kernel_launch(void* const* d_in, const int* in_sizes, int n_in,
                              void* d_out, int out_size, void* d_ws, size_t ws_size,
                              hipStream_t stream) {
    const float* cosine  = (const float*)d_in[0];
    const int*   targets = (const int*)d_in[1];
    float*       out     = (float*)d_out;

    // d_out is re-poisoned to 0xAA before every timed launch; zero it on-stream
    // (async memset is graph-capture legal).
    hipMemsetAsync(out, 0, sizeof(float), stream);

    arcface_loss_kernel<<<NROWS, 256, 0, stream>>>(cosine, targets, out);
}